// Round 3
// baseline (417.663 us; speedup 1.0000x reference)
//
#include <hip/hip_runtime.h>
#include <hip/hip_bf16.h>
#include <stdint.h>

// TernaryLinear: C[8192,4096] = x[8192,4096] @ W[4096,4096]^T + b
// i8 path: W is exactly {-1,0,+1} -> int8 exact; x quantized per-row absmax.
#define M_DIM 8192
#define N_DIM 4096
#define K_DIM 4096
#define BM 128
#define BN 128
#define BKI 64   // i8 K-tile: one mfma_i32_16x16x64_i8 K-step per iteration

typedef int intx4 __attribute__((ext_vector_type(4)));

typedef __attribute__((address_space(1))) void gv_t;
typedef __attribute__((address_space(3))) void lv_t;

// async global->LDS, 16B per lane. LDS dest is wave-uniform base + lane*16
// (per-lane scatter NOT honored on the LDS side; global side is a true gather).
__device__ __forceinline__ void gl2lds16(const void* g, void* l) {
    __builtin_amdgcn_global_load_lds((const gv_t*)g, (lv_t*)l, 16, 0, 0);
}

__device__ __forceinline__ int pack4_scaled(float4 v, float s) {
    int a = __float2int_rn(v.x * s) & 255;
    int b = __float2int_rn(v.y * s) & 255;
    int c = __float2int_rn(v.z * s) & 255;
    int d = __float2int_rn(v.w * s) & 255;
    return a | (b << 8) | (c << 16) | (d << 24);
}

// Fused quant: blocks [0,8192) quantize one x-row each (per-row absmax -> i8);
// blocks [8192, 8192+2048) convert W (exact ternary) fp32 -> i8.
// All loads/stores fully coalesced (lane-contiguous, stride-256 per step).
__global__ __launch_bounds__(256) void quant_fused(
    const float* __restrict__ x, const float* __restrict__ w,
    signed char* __restrict__ xq, signed char* __restrict__ wq,
    float* __restrict__ dq) {
    const int tid = threadIdx.x;
    if (blockIdx.x < M_DIM) {
        const int row = blockIdx.x;
        const float4* p = (const float4*)(x + (size_t)row * K_DIM);
        float4 v0 = p[tid];
        float4 v1 = p[tid + 256];
        float4 v2 = p[tid + 512];
        float4 v3 = p[tid + 768];
        float m = fmaxf(fmaxf(fabsf(v0.x), fabsf(v0.y)), fmaxf(fabsf(v0.z), fabsf(v0.w)));
        m = fmaxf(m, fmaxf(fmaxf(fabsf(v1.x), fabsf(v1.y)), fmaxf(fabsf(v1.z), fabsf(v1.w))));
        m = fmaxf(m, fmaxf(fmaxf(fabsf(v2.x), fabsf(v2.y)), fmaxf(fabsf(v2.z), fabsf(v2.w))));
        m = fmaxf(m, fmaxf(fmaxf(fabsf(v3.x), fabsf(v3.y)), fmaxf(fabsf(v3.z), fabsf(v3.w))));
#pragma unroll
        for (int off = 32; off >= 1; off >>= 1)
            m = fmaxf(m, __shfl_xor(m, off, 64));
        __shared__ float wmax[4];
        if ((tid & 63) == 0) wmax[tid >> 6] = m;
        __syncthreads();
        const float rm = fmaxf(fmaxf(wmax[0], wmax[1]), fmaxf(wmax[2], wmax[3]));
        const float s = rm > 0.f ? 127.f / rm : 0.f;
        if (tid == 0) dq[row] = rm * (1.f / 127.f);
        int* q = (int*)(xq + (size_t)row * K_DIM);
        q[tid]       = pack4_scaled(v0, s);
        q[tid + 256] = pack4_scaled(v1, s);
        q[tid + 512] = pack4_scaled(v2, s);
        q[tid + 768] = pack4_scaled(v3, s);
    } else {
        // W: 4096x4096 fp32 -> 4,194,304 packed dwords; 2048 blocks x 256 thr x 8
        const size_t base = (size_t)(blockIdx.x - M_DIM) * (256 * 8) + tid;
        const float4* p = (const float4*)w;
        int* q = (int*)wq;
#pragma unroll
        for (int j = 0; j < 8; j++) {
            const size_t idx = base + (size_t)j * 256;
            q[idx] = pack4_scaled(p[idx], 1.f);
        }
    }
}

// m97-structure i8 GEMM, B^T input: C[m,n] = (sum_k Aq[m,k]*Bq[n,k])*dq[m] + bias[n]
// 128x128 tile, BK=64, 4 waves (2x2), each wave 64x64 via 4x4 mfma_i32_16x16x64_i8.
// LDS XOR-swizzle: storage slot chunk = global chunk ^ ((row>>1)&3), applied on the
// GLOBAL gather side (LDS side of global_load_lds is forced linear-by-lane).
// Fragment ds_read compensates -> conflict-free b128 reads (each lane-octet spans
// all 32 banks; row stride 64B = 16 banks was the 2-row-alias culprit).
__global__ __launch_bounds__(256, 3) void gemm_bt_i8(
    const signed char* __restrict__ A,   // M x K i8
    const signed char* __restrict__ B,   // N x K i8
    const float* __restrict__ dq,        // M per-row dequant scale
    const float* __restrict__ bias,      // N
    float* __restrict__ C) {             // M x N fp32
    __shared__ signed char sA[BM * BKI]; // 8 KiB
    __shared__ signed char sB[BN * BKI]; // 8 KiB

    const int tid  = threadIdx.x;
    const int lane = tid & 63;
    const int wv   = tid >> 6;
    const int wm   = wv >> 1;
    const int wn   = wv & 1;

    const int row0 = blockIdx.y * BM;
    const int col0 = blockIdx.x * BN;

    // staging: row = 64 bytes = 4 lanes x 16B; each instr pair covers 64 rows.
    const int srow   = wv * 16 + (lane >> 2);
    // LDS slot chunk (forced): lane&3.  Global chunk gathered = slot ^ key,
    // key = (srow>>1)&3 = (lane>>3)&3 (wv*16 contributes 0 mod 4; +64 rows too).
    const int skofs_g = (((lane & 3) ^ ((lane >> 3) & 3))) * 16;
    const int skofs_l = (lane & 3) * 16;

    const signed char* gA = A + (size_t)(row0 + srow) * K_DIM + skofs_g;
    const signed char* gB = B + (size_t)(col0 + srow) * K_DIM + skofs_g;
    const size_t stride64 = (size_t)64 * K_DIM;

    signed char* lA0 = &sA[srow * BKI + skofs_l];
    signed char* lA1 = &sA[(srow + 64) * BKI + skofs_l];
    signed char* lB0 = &sB[srow * BKI + skofs_l];
    signed char* lB1 = &sB[(srow + 64) * BKI + skofs_l];

    // fragment coords: m/n = lane&15, k-chunk kc = lane>>4; unswizzle with
    // key = (fr>>1)&3 (i*16 and wm/wn*64 row offsets are 0 mod 8).
    const int fr = lane & 15;
    const int kc = lane >> 4;
    const int fk = (kc ^ ((fr >> 1) & 3)) * 16;
    const signed char* fA = &sA[(wm * 64 + fr) * BKI + fk];
    const signed char* fB = &sB[(wn * 64 + fr) * BKI + fk];

    intx4 acc[4][4];
#pragma unroll
    for (int i = 0; i < 4; i++)
#pragma unroll
        for (int j = 0; j < 4; j++) acc[i][j] = (intx4)0;

    for (int k0 = 0; k0 < K_DIM; k0 += BKI) {
        __syncthreads();
        gl2lds16(gA,            lA0);
        gl2lds16(gA + stride64, lA1);
        gl2lds16(gB,            lB0);
        gl2lds16(gB + stride64, lB1);
        gA += BKI; gB += BKI;
        __syncthreads();

        intx4 af[4], bf[4];
#pragma unroll
        for (int i = 0; i < 4; i++) af[i] = *(const intx4*)(fA + i * 16 * BKI);
#pragma unroll
        for (int j = 0; j < 4; j++) bf[j] = *(const intx4*)(fB + j * 16 * BKI);
#pragma unroll
        for (int i = 0; i < 4; i++)
#pragma unroll
            for (int j = 0; j < 4; j++)
                acc[i][j] = __builtin_amdgcn_mfma_i32_16x16x64_i8(
                    af[i], bf[j], acc[i][j], 0, 0, 0);
    }

    // epilogue: C/D layout col=lane&15, row=(lane>>4)*4+reg (dtype-independent)
    const int ccol  = lane & 15;
    const int crow4 = (lane >> 4) * 4;
    const int rbase = row0 + wm * 64 + crow4;
    float rs[4][4];
#pragma unroll
    for (int i = 0; i < 4; i++)
#pragma unroll
        for (int r = 0; r < 4; r++) rs[i][r] = dq[rbase + i * 16 + r];
#pragma unroll
    for (int j = 0; j < 4; j++) {
        const int col = col0 + wn * 64 + j * 16 + ccol;
        const float bv = bias[col];
#pragma unroll
        for (int i = 0; i < 4; i++) {
            float* cp = C + (size_t)(rbase + i * 16) * N_DIM + col;
#pragma unroll
            for (int r = 0; r < 4; r++)
                cp[(size_t)r * N_DIM] = (float)acc[i][j][r] * rs[i][r] + bv;
        }
    }
}

// Correctness fallback if workspace is too small.
__global__ __launch_bounds__(256) void naive_ternary(
    const float* __restrict__ x, const float* __restrict__ w,
    const float* __restrict__ bias, float* __restrict__ out) {
    const int col = blockIdx.x * 64 + (threadIdx.x & 63);
    const int row = blockIdx.y * 4 + (threadIdx.x >> 6);
    const float* xr = x + (size_t)row * K_DIM;
    const float* wr = w + (size_t)col * K_DIM;
    float s = 0.f;
    for (int k = 0; k < K_DIM; ++k) s += xr[k] * wr[k];
    out[(size_t)row * N_DIM + col] = s + bias[col];
}

extern "C" void kernel_launch(void* const* d_in, const int* in_sizes, int n_in,
                              void* d_out, int out_size, void* d_ws, size_t ws_size,
                              hipStream_t stream) {
    const float* x    = (const float*)d_in[0];
    const float* w    = (const float*)d_in[1];
    const float* bias = (const float*)d_in[2];
    float* out = (float*)d_out;

    const size_t xN = (size_t)M_DIM * K_DIM;   // 33.55M
    const size_t wN = (size_t)N_DIM * K_DIM;   // 16.78M
    const size_t need = xN + wN + (size_t)M_DIM * sizeof(float);  // ~50.4 MB

    if (ws_size >= need) {
        signed char* xq = (signed char*)d_ws;
        signed char* wq = xq + xN;
        float* dq = (float*)(wq + wN);
        quant_fused<<<M_DIM + 2048, 256, 0, stream>>>(x, w, xq, wq, dq);
        dim3 grid(N_DIM / BN, M_DIM / BM);   // (32, 64)
        gemm_bt_i8<<<grid, 256, 0, stream>>>(xq, wq, dq, bias, out);
    } else {
        dim3 grid(N_DIM / 64, M_DIM / 4);
        naive_ternary<<<grid, 256, 0, stream>>>(x, w, bias, out);
    }
}